// Round 1
// baseline (361.629 us; speedup 1.0000x reference)
//
#include <hip/hip_runtime.h>

#define BATCH 32
#define IMG 512
#define CH 3
#define GOUT 64
#define ROWB (IMG*CH)   // 1536 floats per image row

// ---------------------------------------------------------------------------
// Kernel 1: Gaussian filterbank masks.
// One block per (b, axis, r): computes 512 exp() values for column r,
// block-reduces the normalizer, writes normalized column.
// Ay layout: [b][h][H]  (matches reference (B, C, R)); same for Ax.
// ---------------------------------------------------------------------------
__global__ __launch_bounds__(256) void mask_kernel(const float* __restrict__ tp,
                                                   float* __restrict__ Ay,
                                                   float* __restrict__ Ax) {
    int blk = blockIdx.x;          // ((b*2 + axis)*64 + r)
    int r    = blk & 63;
    int ba   = blk >> 6;
    int axis = ba & 1;
    int b    = ba >> 1;

    const float* p = tp + b*6 + (axis ? 3 : 0);
    float u = p[0], s = p[1], d = p[2];
    float centre = u + (float)r * d;
    float inv_s  = 1.0f / s;

    int t = threadIdx.x;
    float c0 = (float)t;
    float c1 = (float)(t + 256);
    float z0 = (c0 - centre) * inv_s;
    float z1 = (c1 - centre) * inv_s;
    float e0 = __expf(-0.5f * z0 * z0);
    float e1 = __expf(-0.5f * z1 * z1);

    __shared__ float red[256];
    red[t] = e0 + e1;
    __syncthreads();
    #pragma unroll
    for (int ofs = 128; ofs > 0; ofs >>= 1) {
        if (t < ofs) red[t] += red[t + ofs];
        __syncthreads();
    }
    float inv_sum = 1.0f / (red[0] + 1e-8f);

    float* dst = axis ? Ax : Ay;
    dst[((size_t)b*IMG + t      ) * GOUT + r] = e0 * inv_sum;
    dst[((size_t)b*IMG + t + 256) * GOUT + r] = e1 * inv_sum;
}

// ---------------------------------------------------------------------------
// Kernel 2: g[b,H,w,c] = sum_h Ay[b,h,H] * img[b,h,w,c]
// grid = B * 6 * 2; block 256. Each thread owns one flat column j = w*3+c
// and 64 fp32 accumulators (one per H). h split into two halves (parts) so we
// get 384 blocks; partial sums land in g[part]. img is read exactly once.
// Ay reads are block-uniform -> scalar loads; inner loop is 64 v_fmac_f32.
// ---------------------------------------------------------------------------
__global__ __launch_bounds__(256) void stage1_kernel(const float* __restrict__ img,
                                                     const float* __restrict__ Ay,
                                                     float* __restrict__ g) {
    int blk  = blockIdx.x;         // ((b*6 + jc)*2 + part)
    int part = blk & 1;
    int bj   = blk >> 1;
    int jc   = bj % 6;
    int b    = bj / 6;
    int j    = jc * 256 + threadIdx.x;
    int h0   = part * 256;

    float acc[GOUT];
    #pragma unroll
    for (int H = 0; H < GOUT; ++H) acc[H] = 0.0f;

    const float* imgp = img + ((size_t)(b*IMG + h0)) * ROWB + j;
    const float* ayp  = Ay  + ((size_t)(b*IMG + h0)) * GOUT;

    for (int h = 0; h < 256; ++h) {
        float v = imgp[(size_t)h * ROWB];
        #pragma unroll
        for (int H = 0; H < GOUT; ++H)
            acc[H] = fmaf(ayp[h*GOUT + H], v, acc[H]);
    }

    float* gp = g + (size_t)part * ((size_t)BATCH*GOUT*ROWB)
                  + (size_t)b * (GOUT*ROWB) + j;
    #pragma unroll
    for (int H = 0; H < GOUT; ++H) gp[(size_t)H * ROWB] = acc[H];
}

// ---------------------------------------------------------------------------
// Kernel 3: out[b,H,W,c] = sum_w (g0+g1)[b,H,w,c] * Ax[b,w,W]
// grid = B*64 (one block per (b,H)); block 192 = (W=64) x (c=3).
// Ax loads coalesced across W; g loads broadcast within a wave (c uniform).
// ---------------------------------------------------------------------------
__global__ __launch_bounds__(192) void stage2_kernel(const float* __restrict__ g,
                                                     const float* __restrict__ Ax,
                                                     float* __restrict__ out) {
    int blk = blockIdx.x;          // b*64 + H
    int H = blk & 63;
    int b = blk >> 6;
    int t = threadIdx.x;
    int W = t & 63;
    int c = t >> 6;                // 0..2

    const float* g0  = g + (size_t)b * (GOUT*ROWB) + (size_t)H * ROWB + c;
    const float* g1  = g0 + (size_t)BATCH * GOUT * ROWB;
    const float* axp = Ax + (size_t)b * IMG * GOUT + W;

    float acc = 0.0f;
    #pragma unroll 4
    for (int w = 0; w < IMG; ++w) {
        float gv = g0[w*CH] + g1[w*CH];
        acc = fmaf(gv, axp[w*GOUT], acc);
    }
    out[(((size_t)b*GOUT + H) * GOUT + W) * CH + c] = acc;
}

// ---------------------------------------------------------------------------
// Launch. Workspace layout (floats):
//   Ay : B*512*64            = 1,048,576
//   Ax : B*512*64            = 1,048,576
//   g  : 2 * B*64*1536       = 6,291,456   (two h-half partials)
// total 8,388,608 floats = 32 MB of d_ws.
// ---------------------------------------------------------------------------
extern "C" void kernel_launch(void* const* d_in, const int* in_sizes, int n_in,
                              void* d_out, int out_size, void* d_ws, size_t ws_size,
                              hipStream_t stream) {
    const float* img = (const float*)d_in[0];
    const float* tp  = (const float*)d_in[1];
    float* out = (float*)d_out;

    float* ws = (float*)d_ws;
    float* Ay = ws;
    float* Ax = Ay + (size_t)BATCH * IMG * GOUT;
    float* g  = Ax + (size_t)BATCH * IMG * GOUT;

    mask_kernel  <<<BATCH * 2 * GOUT, 256, 0, stream>>>(tp, Ay, Ax);
    stage1_kernel<<<BATCH * 6 * 2,    256, 0, stream>>>(img, Ay, g);
    stage2_kernel<<<BATCH * GOUT,     192, 0, stream>>>(g, Ax, out);
}

// Round 2
// 244.533 us; speedup vs baseline: 1.4789x; 1.4789x over previous
//
#include <hip/hip_runtime.h>

#define BATCH 32
#define IMG 512
#define CH 3
#define GOUT 64
#define ROWB (IMG*CH)   // 1536 floats per image row

// ---------------------------------------------------------------------------
// Kernel 1: Gaussian filterbank masks (unchanged from round 0 — cheap).
// Ay layout: [b][h][H]; Ax: [b][w][W].
// ---------------------------------------------------------------------------
__global__ __launch_bounds__(256) void mask_kernel(const float* __restrict__ tp,
                                                   float* __restrict__ Ay,
                                                   float* __restrict__ Ax) {
    int blk = blockIdx.x;          // ((b*2 + axis)*64 + r)
    int r    = blk & 63;
    int ba   = blk >> 6;
    int axis = ba & 1;
    int b    = ba >> 1;

    const float* p = tp + b*6 + (axis ? 3 : 0);
    float u = p[0], s = p[1], d = p[2];
    float centre = u + (float)r * d;
    float inv_s  = 1.0f / s;

    int t = threadIdx.x;
    float z0 = ((float)t        - centre) * inv_s;
    float z1 = ((float)(t + 256) - centre) * inv_s;
    float e0 = __expf(-0.5f * z0 * z0);
    float e1 = __expf(-0.5f * z1 * z1);

    __shared__ float red[256];
    red[t] = e0 + e1;
    __syncthreads();
    #pragma unroll
    for (int ofs = 128; ofs > 0; ofs >>= 1) {
        if (t < ofs) red[t] += red[t + ofs];
        __syncthreads();
    }
    float inv_sum = 1.0f / (red[0] + 1e-8f);

    float* dst = axis ? Ax : Ay;
    dst[((size_t)b*IMG + t      ) * GOUT + r] = e0 * inv_sum;
    dst[((size_t)b*IMG + t + 256) * GOUT + r] = e1 * inv_sum;
}

// ---------------------------------------------------------------------------
// Kernel 2: g[b,H,wc] = sum_h Ay[b,h,H] * img[b,h,wc]
// LDS-tiled GEMM: per block, C[64H x 64wc] = Ay^T[64x512] * img[512x64].
// grid = 32 b * 24 wc-tiles = 768 blocks; block = 128 threads (2 waves).
// K in 16 chunks of 32. Micro-tile 4H x 8wc per thread (32 scalar accs,
// fully unrolled -> guaranteed register promotion; round-0 failure mode
// was acc[64] not being promoted, VGPR_Count=36).
// Per 32 FMAs: 3 ds_read_b128 (vs round-0's 64 global loads per 64 FMAs).
// ---------------------------------------------------------------------------
__global__ __launch_bounds__(128) void stage1_kernel(const float* __restrict__ img,
                                                     const float* __restrict__ Ay,
                                                     float* __restrict__ g) {
    __shared__ float As[32*64];  // As[kk][H]  = Ay[b][h0+kk][H]
    __shared__ float Bs[32*64];  // Bs[kk][j]  = img[b][h0+kk][wc0+j]

    int tile = blockIdx.x % 24;
    int b    = blockIdx.x / 24;
    int wc0  = tile * 64;
    int tid  = threadIdx.x;
    int H0   = (tid >> 3) * 4;   // 16 H-groups of 4
    int w0   = (tid & 7) * 8;    // 8 wc-groups of 8

    float acc[4][8];
    #pragma unroll
    for (int i = 0; i < 4; ++i)
        #pragma unroll
        for (int j = 0; j < 8; ++j) acc[i][j] = 0.0f;

    const float* ayb = Ay  + (size_t)b * IMG * GOUT;
    const float* imb = img + (size_t)b * IMG * ROWB + wc0;

    for (int h0 = 0; h0 < IMG; h0 += 32) {
        // --- stage As: Ay rows h0..h0+31 are 2048 CONTIGUOUS floats ---
        {
            const float4* src = (const float4*)(ayb + h0 * GOUT);
            float4* dst = (float4*)As;
            #pragma unroll
            for (int k = 0; k < 4; ++k)
                dst[tid + k*128] = src[tid + k*128];
        }
        // --- stage Bs: 32 img rows of 64 consecutive floats (stride ROWB) ---
        {
            float4* dst = (float4*)Bs;
            #pragma unroll
            for (int k = 0; k < 4; ++k) {
                int f  = tid + k*128;        // 0..511 float4 index
                int kk = f >> 4;             // tile row
                int jj = f & 15;             // float4 within row
                dst[f] = *(const float4*)(imb + (size_t)(h0 + kk) * ROWB + jj*4);
            }
        }
        __syncthreads();

        #pragma unroll
        for (int kk = 0; kk < 32; ++kk) {
            float4 a  = *(const float4*)&As[kk*64 + H0];
            float4 p0 = *(const float4*)&Bs[kk*64 + w0];
            float4 p1 = *(const float4*)&Bs[kk*64 + w0 + 4];
            float av[4] = {a.x, a.y, a.z, a.w};
            float bv[8] = {p0.x, p0.y, p0.z, p0.w, p1.x, p1.y, p1.z, p1.w};
            #pragma unroll
            for (int i = 0; i < 4; ++i)
                #pragma unroll
                for (int j = 0; j < 8; ++j)
                    acc[i][j] = fmaf(av[i], bv[j], acc[i][j]);
        }
        __syncthreads();
    }

    // epilogue: g[b][H0+i][wc0 + w0 + 0..7]
    float* gb = g + (size_t)b * GOUT * ROWB + wc0 + w0;
    #pragma unroll
    for (int i = 0; i < 4; ++i) {
        float4 lo = {acc[i][0], acc[i][1], acc[i][2], acc[i][3]};
        float4 hi = {acc[i][4], acc[i][5], acc[i][6], acc[i][7]};
        float4* dst = (float4*)(gb + (size_t)(H0 + i) * ROWB);
        dst[0] = lo;
        dst[1] = hi;
    }
}

// ---------------------------------------------------------------------------
// Kernel 3: out[b,H,W,c] = sum_w g[b,H,w,c] * Ax[b,w,W]
// grid = B*64 (block per (b,H)); block 192 = (W=64) x (c=3).
// Ax loads coalesced across W-lanes; g loads broadcast (same addr per wave).
// 4 independent accumulators to break the serial FMA dependency chain.
// ---------------------------------------------------------------------------
__global__ __launch_bounds__(192) void stage2_kernel(const float* __restrict__ g,
                                                     const float* __restrict__ Ax,
                                                     float* __restrict__ out) {
    int blk = blockIdx.x;          // b*64 + H
    int H = blk & 63;
    int b = blk >> 6;
    int t = threadIdx.x;
    int W = t & 63;
    int c = t >> 6;                // 0..2

    const float* gp  = g  + (size_t)b * (GOUT*ROWB) + (size_t)H * ROWB + c;
    const float* axp = Ax + (size_t)b * IMG * GOUT + W;

    float a0 = 0.f, a1 = 0.f, a2 = 0.f, a3 = 0.f;
    #pragma unroll 2
    for (int w = 0; w < IMG; w += 4) {
        a0 = fmaf(gp[(w+0)*CH], axp[(size_t)(w+0)*GOUT], a0);
        a1 = fmaf(gp[(w+1)*CH], axp[(size_t)(w+1)*GOUT], a1);
        a2 = fmaf(gp[(w+2)*CH], axp[(size_t)(w+2)*GOUT], a2);
        a3 = fmaf(gp[(w+3)*CH], axp[(size_t)(w+3)*GOUT], a3);
    }
    out[(((size_t)b*GOUT + H) * GOUT + W) * CH + c] = (a0 + a1) + (a2 + a3);
}

// ---------------------------------------------------------------------------
// Launch. Workspace layout (floats):
//   Ay : B*512*64      = 1,048,576
//   Ax : B*512*64      = 1,048,576
//   g  : B*64*1536     = 3,145,728   (no k-split this round)
// total 5,242,880 floats = 20 MB of d_ws.
// ---------------------------------------------------------------------------
extern "C" void kernel_launch(void* const* d_in, const int* in_sizes, int n_in,
                              void* d_out, int out_size, void* d_ws, size_t ws_size,
                              hipStream_t stream) {
    const float* img = (const float*)d_in[0];
    const float* tp  = (const float*)d_in[1];
    float* out = (float*)d_out;

    float* ws = (float*)d_ws;
    float* Ay = ws;
    float* Ax = Ay + (size_t)BATCH * IMG * GOUT;
    float* g  = Ax + (size_t)BATCH * IMG * GOUT;

    mask_kernel  <<<BATCH * 2 * GOUT, 256, 0, stream>>>(tp, Ay, Ax);
    stage1_kernel<<<BATCH * 24,       128, 0, stream>>>(img, Ay, g);
    stage2_kernel<<<BATCH * GOUT,     192, 0, stream>>>(g, Ax, out);
}

// Round 3
// 192.288 us; speedup vs baseline: 1.8807x; 1.2717x over previous
//
#include <hip/hip_runtime.h>

#define BATCH 32
#define IMG 512
#define CH 3
#define GOUT 64
#define ROWB (IMG*CH)   // 1536 floats per image row
#define GPART ((size_t)BATCH*GOUT*ROWB)  // one K-split partial of g

// ---------------------------------------------------------------------------
// Kernel 1: Gaussian filterbank masks. One WAVE per (b, axis, r).
// 8 exps/lane, butterfly shuffle reduction, no barriers.
// Ay layout: [b][h][H]; Ax: [b][w][W].
// ---------------------------------------------------------------------------
__global__ __launch_bounds__(64) void mask_kernel(const float* __restrict__ tp,
                                                  float* __restrict__ Ay,
                                                  float* __restrict__ Ax) {
    int blk  = blockIdx.x;         // ((b*2 + axis)*64 + r)
    int r    = blk & 63;
    int axis = (blk >> 6) & 1;
    int b    = blk >> 7;

    const float* p = tp + b*6 + (axis ? 3 : 0);
    float u = p[0], s = p[1], d = p[2];
    float centre = u + (float)r * d;
    float inv_s  = 1.0f / s;

    int lane = threadIdx.x;
    float e[8];
    float sum = 0.0f;
    #pragma unroll
    for (int i = 0; i < 8; ++i) {
        float z = ((float)(i*64 + lane) - centre) * inv_s;
        e[i] = __expf(-0.5f * z * z);
        sum += e[i];
    }
    #pragma unroll
    for (int m = 1; m < 64; m <<= 1)
        sum += __shfl_xor(sum, m, 64);
    float inv_sum = 1.0f / (sum + 1e-8f);

    float* dst = axis ? Ax : Ay;
    #pragma unroll
    for (int i = 0; i < 8; ++i)
        dst[((size_t)b*IMG + i*64 + lane) * GOUT + r] = e[i] * inv_sum;
}

// ---------------------------------------------------------------------------
// Kernel 2: g[part][b,H,wc] = sum_{h in part} Ay[b,h,H] * img[b,h,wc]
// Tiled GEMM, 256 threads (4 waves), 4H x 4wc micro-tile (b128+b128 -> 16 FMA).
// K-split 2 over h-halves: grid = 32b * 24 wctiles * 2 parts = 1536 blocks
// -> 6 blocks/CU * 4 waves = 24 waves/CU (round-2 failure: 6 waves/CU, 13% occ).
// ---------------------------------------------------------------------------
__global__ __launch_bounds__(256) void stage1_kernel(const float* __restrict__ img,
                                                     const float* __restrict__ Ay,
                                                     float* __restrict__ g) {
    __shared__ float As[32*64];  // As[kk][H]
    __shared__ float Bs[32*64];  // Bs[kk][j]

    int part = blockIdx.x & 1;
    int bt   = blockIdx.x >> 1;
    int tile = bt % 24;
    int b    = bt / 24;
    int wc0  = tile * 64;
    int tid  = threadIdx.x;
    int H0   = (tid >> 4) * 4;   // 16 H-groups of 4
    int w0   = (tid & 15) * 4;   // 16 wc-groups of 4

    float acc[4][4];
    #pragma unroll
    for (int i = 0; i < 4; ++i)
        #pragma unroll
        for (int j = 0; j < 4; ++j) acc[i][j] = 0.0f;

    const float* ayb = Ay  + ((size_t)b * IMG + part*256) * GOUT;
    const float* imb = img + ((size_t)b * IMG + part*256) * ROWB + wc0;

    for (int h0 = 0; h0 < 256; h0 += 32) {
        // stage As: 2048 contiguous floats (Ay rows are contiguous)
        {
            const float4* src = (const float4*)(ayb + h0 * GOUT);
            float4* dst = (float4*)As;
            dst[tid]       = src[tid];
            dst[tid + 256] = src[tid + 256];
        }
        // stage Bs: 32 img rows of 64 floats (16 float4 each, stride ROWB)
        {
            float4* dst = (float4*)Bs;
            #pragma unroll
            for (int k = 0; k < 2; ++k) {
                int f  = tid + k*256;
                int kk = f >> 4;
                int jj = f & 15;
                dst[f] = *(const float4*)(imb + (size_t)(h0 + kk) * ROWB + jj*4);
            }
        }
        __syncthreads();

        #pragma unroll
        for (int kk = 0; kk < 32; ++kk) {
            float4 a = *(const float4*)&As[kk*64 + H0];
            float4 p = *(const float4*)&Bs[kk*64 + w0];
            float av[4] = {a.x, a.y, a.z, a.w};
            float bv[4] = {p.x, p.y, p.z, p.w};
            #pragma unroll
            for (int i = 0; i < 4; ++i)
                #pragma unroll
                for (int j = 0; j < 4; ++j)
                    acc[i][j] = fmaf(av[i], bv[j], acc[i][j]);
        }
        __syncthreads();
    }

    float* gp = g + (size_t)part * GPART + (size_t)b * GOUT * ROWB + wc0 + w0;
    #pragma unroll
    for (int i = 0; i < 4; ++i) {
        float4 v = {acc[i][0], acc[i][1], acc[i][2], acc[i][3]};
        *(float4*)(gp + (size_t)(H0 + i) * ROWB) = v;
    }
}

// ---------------------------------------------------------------------------
// Kernel 3: out[b,H,W,c] = sum_w (g0+g1)[b,H,w,c] * Ax[b,w,W]
// Block per (b,H), 256 threads = 4 waves. Stage g row (1536 floats, both
// K-parts summed) into LDS once. Each wave owns a 128-w quarter; lane = W.
// Per w: 1 coalesced Ax load + broadcast LDS g reads + 3 FMAs (vs round-2's
// 2 global loads per 1 FMA). Cross-wave reduce in LDS, coalesced stores.
// ---------------------------------------------------------------------------
__global__ __launch_bounds__(256) void stage2_kernel(const float* __restrict__ g,
                                                     const float* __restrict__ Ax,
                                                     float* __restrict__ out) {
    __shared__ float gs[ROWB];       // summed g row
    __shared__ float red[4*192];     // per-wave partial out

    int blk = blockIdx.x;            // b*64 + H
    int H = blk & 63;
    int b = blk >> 6;
    int t = threadIdx.x;
    int wave = t >> 6;
    int W    = t & 63;

    // stage g row: 768 float2, 3 per thread, both parts summed
    {
        const float2* g0 = (const float2*)(g + (size_t)b * GOUT * ROWB + (size_t)H * ROWB);
        const float2* g1 = (const float2*)((const float*)g0 + GPART);
        float2* dst = (float2*)gs;
        #pragma unroll
        for (int k = 0; k < 3; ++k) {
            int i = t + k*256;
            float2 a = g0[i], c = g1[i];
            float2 v = {a.x + c.x, a.y + c.y};
            dst[i] = v;
        }
    }
    __syncthreads();

    const float* axp = Ax + (size_t)b * IMG * GOUT + W;
    float a0 = 0.f, a1 = 0.f, a2 = 0.f;
    int wbase = wave * 128;
    #pragma unroll 4
    for (int k = 0; k < 128; ++k) {
        int w = wbase + k;
        float ax = axp[(size_t)w * GOUT];
        a0 = fmaf(gs[w*CH + 0], ax, a0);
        a1 = fmaf(gs[w*CH + 1], ax, a1);
        a2 = fmaf(gs[w*CH + 2], ax, a2);
    }

    red[wave*192 + 0*64 + W] = a0;
    red[wave*192 + 1*64 + W] = a1;
    red[wave*192 + 2*64 + W] = a2;
    __syncthreads();

    if (t < 192) {
        int c  = t % 3;
        int Wo = t / 3;
        float v = red[0*192 + c*64 + Wo] + red[1*192 + c*64 + Wo]
                + red[2*192 + c*64 + Wo] + red[3*192 + c*64 + Wo];
        out[(((size_t)b*GOUT + H) * GOUT) * CH + t] = v;
    }
}

// ---------------------------------------------------------------------------
// Workspace (floats): Ay 1,048,576 | Ax 1,048,576 | g 2*3,145,728
// total 8,388,608 floats = 32 MB.
// ---------------------------------------------------------------------------
extern "C" void kernel_launch(void* const* d_in, const int* in_sizes, int n_in,
                              void* d_out, int out_size, void* d_ws, size_t ws_size,
                              hipStream_t stream) {
    const float* img = (const float*)d_in[0];
    const float* tp  = (const float*)d_in[1];
    float* out = (float*)d_out;

    float* ws = (float*)d_ws;
    float* Ay = ws;
    float* Ax = Ay + (size_t)BATCH * IMG * GOUT;
    float* g  = Ax + (size_t)BATCH * IMG * GOUT;

    mask_kernel  <<<BATCH * 2 * GOUT,  64, 0, stream>>>(tp, Ay, Ax);
    stage1_kernel<<<BATCH * 24 * 2,   256, 0, stream>>>(img, Ay, g);
    stage2_kernel<<<BATCH * GOUT,     256, 0, stream>>>(g, Ax, out);
}

// Round 4
// 190.099 us; speedup vs baseline: 1.9023x; 1.0115x over previous
//
#include <hip/hip_runtime.h>

#define BATCH 32
#define IMG 512
#define CH 3
#define GOUT 64
#define ROWB (IMG*CH)   // 1536 floats per image row

typedef __attribute__((ext_vector_type(8))) short  short8;   // 8 bf16 = 4 VGPRs
typedef __attribute__((ext_vector_type(4))) float  floatx4;  // MFMA 16x16 acc

__device__ __forceinline__ unsigned short f2bf(float x) {
    // round-to-nearest-even fp32 -> bf16 (no NaN handling; inputs are finite)
    unsigned u = __builtin_bit_cast(unsigned, x);
    u += 0x7FFFu + ((u >> 16) & 1u);
    return (unsigned short)(u >> 16);
}

// ---------------------------------------------------------------------------
// Kernel 1: Gaussian filterbank masks, written TRANSPOSED in bf16.
// AyT[b][H][h], AxT[b][W][w]  (k = h/w contiguous -> MFMA frags are b128).
// One wave per (b, axis, r); shuffle reduction; coalesced 2B stores.
// ---------------------------------------------------------------------------
__global__ __launch_bounds__(64) void mask_kernel(const float* __restrict__ tp,
                                                  unsigned short* __restrict__ AyT,
                                                  unsigned short* __restrict__ AxT) {
    int blk  = blockIdx.x;         // ((b*2 + axis)*64 + r)
    int r    = blk & 63;
    int axis = (blk >> 6) & 1;
    int b    = blk >> 7;

    const float* p = tp + b*6 + (axis ? 3 : 0);
    float u = p[0], s = p[1], d = p[2];
    float centre = u + (float)r * d;
    float inv_s  = 1.0f / s;

    int lane = threadIdx.x;
    float e[8];
    float sum = 0.0f;
    #pragma unroll
    for (int i = 0; i < 8; ++i) {
        float z = ((float)(i*64 + lane) - centre) * inv_s;
        e[i] = __expf(-0.5f * z * z);
        sum += e[i];
    }
    #pragma unroll
    for (int m = 1; m < 64; m <<= 1)
        sum += __shfl_xor(sum, m, 64);
    float inv_sum = 1.0f / (sum + 1e-8f);

    unsigned short* dst = (axis ? AxT : AyT) + ((size_t)b*GOUT + r) * IMG;
    #pragma unroll
    for (int i = 0; i < 8; ++i)
        dst[i*64 + lane] = f2bf(e[i] * inv_sum);
}

// ---------------------------------------------------------------------------
// Kernel 2: g[b][c][H][w] = sum_h Ay[b,h,H] * img[b,h,w,c]   (planar output)
// LDS-FREE bf16 MFMA GEMM (round-3 stage1 was LDS-issue-bound: 2 B/FMA of
// ds_read_b128 -> ~61 us floor). Per block: 64H x 64wc tile, 4 waves each own
// 16 wc. Per K-chunk-32 per wave:
//   B-frag: 8 strided global b32 img loads (one instr = 4 rows x 64 B, all
//           bytes consumed across the tile; L2 merges) + in-reg bf16 cvt
//   A-frags: 4 x dwordx4 from AyT (k-contiguous; L2-hot, 64 KB per image)
//   4 x v_mfma_f32_16x16x32_bf16
// No __syncthreads anywhere. Grid 32*24 = 768 blocks (3/CU, 12 waves/CU).
// ---------------------------------------------------------------------------
__global__ __launch_bounds__(256) void stage1_kernel(const float* __restrict__ img,
                                                     const unsigned short* __restrict__ AyT,
                                                     float* __restrict__ gP) {
    int tile = blockIdx.x % 24;
    int b    = blockIdx.x / 24;
    int tid  = threadIdx.x;
    int wave = tid >> 6;
    int lane = tid & 63;
    int n16  = lane & 15;          // MFMA col (wc within 16-tile)
    int q    = lane >> 4;          // quad: k = q*8 + j
    int wc   = tile*64 + wave*16 + n16;

    floatx4 acc[4];
    #pragma unroll
    for (int mt = 0; mt < 4; ++mt) acc[mt] = (floatx4){0.f, 0.f, 0.f, 0.f};

    const unsigned short* ayb = AyT + ((size_t)b*GOUT + n16) * IMG;  // m = lane&15

    for (int h0 = 0; h0 < IMG; h0 += 32) {
        // B fragment: img[h0+q*8+j][wc], j = 0..7
        const float* bp = img + ((size_t)(b*IMG + h0 + q*8)) * ROWB + wc;
        short8 bf;
        #pragma unroll
        for (int j = 0; j < 8; ++j)
            bf[j] = (short)f2bf(bp[(size_t)j * ROWB]);

        #pragma unroll
        for (int mt = 0; mt < 4; ++mt) {
            // A fragment: AyT[b][mt*16 + m][h0 + q*8 + j]
            short8 af = *(const short8*)(ayb + (size_t)mt*16*IMG + h0 + q*8);
            acc[mt] = __builtin_amdgcn_mfma_f32_16x16x32_bf16(af, bf, acc[mt], 0, 0, 0);
        }
    }

    // Epilogue: C/D layout col=lane&15 (wc), row=q*4+reg (H within 16-tile).
    // Planar scatter: wc -> (w, c); every byte of gP written -> L2 combines.
    int c = wc % 3, w = wc / 3;
    float* gb = gP + ((size_t)(b*CH + c) * GOUT) * IMG + w;
    #pragma unroll
    for (int mt = 0; mt < 4; ++mt) {
        int Hbase = mt*16 + q*4;
        #pragma unroll
        for (int reg = 0; reg < 4; ++reg)
            gb[(size_t)(Hbase + reg) * IMG] = acc[mt][reg];
    }
}

// ---------------------------------------------------------------------------
// Kernel 3: out[b,H,W,c] += sum_{w in part} g[b,c,H,w] * Ax[b,w,W]
// bf16 MFMA, LDS-free. Grid = (b,c,part) = 32*3*4 = 384 blocks; K-split 4
// over w with fp32 atomicAdd into zeroed d_out. 4 waves split H (16 each).
// A-frag: g planar fp32 (2 x b128 + cvt); B-frag: AxT bf16 (1 x b128).
// ---------------------------------------------------------------------------
__global__ __launch_bounds__(256) void stage2_kernel(const float* __restrict__ gP,
                                                     const unsigned short* __restrict__ AxT,
                                                     float* __restrict__ out) {
    int blk  = blockIdx.x;         // ((b*3 + c)*4 + part)
    int part = blk & 3;
    int bc   = blk >> 2;
    int c    = bc % 3;
    int b    = bc / 3;
    int tid  = threadIdx.x;
    int wm   = tid >> 6;           // wave's H-strip (16 rows)
    int lane = tid & 63;
    int n16  = lane & 15;
    int q    = lane >> 4;

    floatx4 acc[4];
    #pragma unroll
    for (int nt = 0; nt < 4; ++nt) acc[nt] = (floatx4){0.f, 0.f, 0.f, 0.f};

    const float*          ga  = gP  + ((size_t)(b*CH + c) * GOUT + wm*16 + n16) * IMG;
    const unsigned short* axb = AxT + ((size_t)b*GOUT + n16) * IMG;

    #pragma unroll
    for (int cc = 0; cc < 4; ++cc) {
        int w0 = part*128 + cc*32;
        // A fragment: g[b][c][H = wm*16 + m][w0 + q*8 + j] fp32 -> bf16
        const float* ap = ga + w0 + q*8;
        short8 af;
        #pragma unroll
        for (int j = 0; j < 8; ++j)
            af[j] = (short)f2bf(ap[j]);

        #pragma unroll
        for (int nt = 0; nt < 4; ++nt) {
            // B fragment: AxT[b][nt*16 + n][w0 + q*8 + j]  (bf16, contiguous)
            short8 bf = *(const short8*)(axb + (size_t)nt*16*IMG + w0 + q*8);
            acc[nt] = __builtin_amdgcn_mfma_f32_16x16x32_bf16(af, bf, acc[nt], 0, 0, 0);
        }
    }

    // Epilogue: H = wm*16 + q*4 + reg, W = nt*16 + n16; atomic K-reduction.
    #pragma unroll
    for (int nt = 0; nt < 4; ++nt) {
        int W = nt*16 + n16;
        #pragma unroll
        for (int reg = 0; reg < 4; ++reg) {
            int H = wm*16 + q*4 + reg;
            atomicAdd(out + (((size_t)b*GOUT + H) * GOUT + W) * CH + c, acc[nt][reg]);
        }
    }
}

// ---------------------------------------------------------------------------
// Workspace: AyT 2 MB bf16 | AxT 2 MB bf16 | gP 12.6 MB fp32  (~17 MB).
// ---------------------------------------------------------------------------
extern "C" void kernel_launch(void* const* d_in, const int* in_sizes, int n_in,
                              void* d_out, int out_size, void* d_ws, size_t ws_size,
                              hipStream_t stream) {
    const float* img = (const float*)d_in[0];
    const float* tp  = (const float*)d_in[1];
    float* out = (float*)d_out;

    unsigned short* AyT = (unsigned short*)d_ws;
    unsigned short* AxT = AyT + (size_t)BATCH * GOUT * IMG;
    float*          gP  = (float*)(AxT + (size_t)BATCH * GOUT * IMG);

    hipMemsetAsync(d_out, 0, (size_t)out_size * sizeof(float), stream);
    mask_kernel  <<<BATCH * 2 * GOUT,  64, 0, stream>>>(tp, AyT, AxT);
    stage1_kernel<<<BATCH * 24,       256, 0, stream>>>(img, AyT, gP);
    stage2_kernel<<<BATCH * CH * 4,   256, 0, stream>>>(gP, AxT, out);
}